// Round 5
// baseline (150.665 us; speedup 1.0000x reference)
//
#include <hip/hip_runtime.h>
#include <hip/hip_fp16.h>

// ImportancePooling: N=100000, K=32, D=64.
// Round-8: 8-nodes-per-wave uint4 gather (MLP/latency fix).
//  - staged fp16 x: 12.8 MB, L2/L3-resident; row = 64 fp16 = 128 B = 8 x u32x4
//  - lane l serves node (l>>3), feature block (l&7): one global_load_dwordx4
//    pulls 8 random rows x 128B = 1KB per instruction (4x fewer gather instrs,
//    4x more bytes in flight per wave than the 2-node half2 version)
//  - headers loaded transposed ([k][node]) so per-k (w,idx) broadcast is a
//    compile-time-addressed ds_bpermute
//  - nontemporal hints on read-once headers + output store
//  - __launch_bounds__(256,8) pins VGPR<=64 so 8 waves/SIMD survive
// Round-7 bug: gather stride was 4 u32x4/row; correct is 8 (128 B / 16 B).

#define K_NBR 32
#define D_FEAT 64

typedef float f32x4 __attribute__((ext_vector_type(4)));
typedef unsigned int u32x2 __attribute__((ext_vector_type(2)));
typedef unsigned int u32x4 __attribute__((ext_vector_type(4)));

static __device__ __forceinline__ __half2 u32_as_h2(unsigned int u) {
  __half2 h;
  __builtin_memcpy(&h, &u, 4);
  return h;
}

static __device__ __forceinline__ unsigned int h2_as_u32(__half2 h) {
  unsigned int u;
  __builtin_memcpy(&u, &h, 4);
  return u;
}

__global__ __launch_bounds__(256) void ImportancePooling_28424093564958_convert(
    const f32x4* __restrict__ x4, u32x2* __restrict__ xh4, int n4) {
  const int i = blockIdx.x * blockDim.x + threadIdx.x;
  if (i < n4) {
    const f32x4 v = __builtin_nontemporal_load(&x4[i]);  // read-once stream
    const __half2 a = __floats2half2_rn(v.x, v.y);
    const __half2 b = __floats2half2_rn(v.z, v.w);
    u32x2 u;
    u.x = h2_as_u32(a);
    u.y = h2_as_u32(b);
    xh4[i] = u;  // regular store: gather kernel wants this in L2
  }
}

__global__ __launch_bounds__(256, 8) void ImportancePooling_28424093564958_kernel(
    const u32x4* __restrict__ xh4,      // [N, 8] u32x4 view of fp16 x rows (128 B/row)
    const int* __restrict__ neighbors,  // [N, 32]
    const float* __restrict__ weights,  // [N, 32]
    f32x4* __restrict__ out4,           // [N, 16] f32x4 view of out
    int Nw) {                           // Nw = N/8 (waves)
  const int wave_id = (int)((blockIdx.x * blockDim.x + threadIdx.x) >> 6);
  const int lane = threadIdx.x & 63;
  if (wave_id >= Nw) return;

  const int g = lane >> 3;   // node sub-index 0..7 (gather phase)
  const int f = lane & 7;    // 16B feature block within the 128B row
  const int gb4 = g << 2;    // bpermute byte base for node g
  const long hbase = (long)wave_id * 256;  // 8 nodes * 32 header elements

  // Transposed header load: reg j, lane l holds header[(l&7)*32 + j*8 + (l>>3)]
  // i.e. node (l&7), neighbor k = j*8 + (l>>3). Strided within a 1KB block;
  // L1 absorbs the re-touch across j. nt: read-once stream.
  int wb[4], nb[4];
  {
    const long e0 = hbase + f * 32 + g;
    wb[0] = __float_as_int(__builtin_nontemporal_load(&weights[e0]));
    wb[1] = __float_as_int(__builtin_nontemporal_load(&weights[e0 + 8]));
    wb[2] = __float_as_int(__builtin_nontemporal_load(&weights[e0 + 16]));
    wb[3] = __float_as_int(__builtin_nontemporal_load(&weights[e0 + 24]));
    nb[0] = __builtin_nontemporal_load(&neighbors[e0]);
    nb[1] = __builtin_nontemporal_load(&neighbors[e0 + 8]);
    nb[2] = __builtin_nontemporal_load(&neighbors[e0 + 16]);
    nb[3] = __builtin_nontemporal_load(&neighbors[e0 + 24]);
  }

  // wsum for node (lane&7): per-lane partial over 4 k's, then butterfly over
  // the 8 lanes sharing (lane&7) (xor 8/16/32 preserves the &7 class).
  float s = __int_as_float(wb[0]) + __int_as_float(wb[1]) +
            __int_as_float(wb[2]) + __int_as_float(wb[3]);
  s += __shfl_xor(s, 8, 64);
  s += __shfl_xor(s, 16, 64);
  s += __shfl_xor(s, 32, 64);
  const float invp = (s > 0.0f) ? (1.0f / s) : 1.0f;
  // lane needs inv of node (lane>>3); it lives at lane g (g<8 -> g&7==g).
  const float inv = __int_as_float(
      __builtin_amdgcn_ds_bpermute(gb4, __float_as_int(invp)));

  float acc[8];
#pragma unroll
  for (int i = 0; i < 8; ++i) acc[i] = 0.0f;

#pragma unroll
  for (int k = 0; k < K_NBR; ++k) {
    // (w, idx) of node (l>>3), neighbor k sits at lane ((k&7)<<3) | (l>>3)
    // of register (k>>3) -- all compile-time under full unroll.
    const int addr = ((k & 7) << 5) + gb4;
    const float wk =
        __int_as_float(__builtin_amdgcn_ds_bpermute(addr, wb[k >> 3]));
    const int idx = __builtin_amdgcn_ds_bpermute(addr, nb[k >> 3]);
    // 8 rows x 128B = 1KB per wave instruction; 32-bit offset (12.8MB array).
    const u32x4 h = xh4[(unsigned)idx * 8u + (unsigned)f];
    const __half2 p0 = u32_as_h2(h.x);
    const __half2 p1 = u32_as_h2(h.y);
    const __half2 p2 = u32_as_h2(h.z);
    const __half2 p3 = u32_as_h2(h.w);
    acc[0] = fmaf(wk, __low2float(p0), acc[0]);   // v_fma_mix_f32
    acc[1] = fmaf(wk, __high2float(p0), acc[1]);
    acc[2] = fmaf(wk, __low2float(p1), acc[2]);
    acc[3] = fmaf(wk, __high2float(p1), acc[3]);
    acc[4] = fmaf(wk, __low2float(p2), acc[4]);
    acc[5] = fmaf(wk, __high2float(p2), acc[5]);
    acc[6] = fmaf(wk, __low2float(p3), acc[6]);
    acc[7] = fmaf(wk, __high2float(p3), acc[7]);
  }

  f32x4 o0, o1;
  o0.x = acc[0] * inv; o0.y = acc[1] * inv;
  o0.z = acc[2] * inv; o0.w = acc[3] * inv;
  o1.x = acc[4] * inv; o1.y = acc[5] * inv;
  o1.z = acc[6] * inv; o1.w = acc[7] * inv;
  // node (wave_id*8+g), feature block f -> f32x4 index node*16 + f*2.
  // Wave covers 2KB contiguous. nt: streaming write-once output.
  const unsigned obase =
      ((unsigned)wave_id * 8u + (unsigned)g) * 16u + (unsigned)f * 2u;
  __builtin_nontemporal_store(o0, &out4[obase]);
  __builtin_nontemporal_store(o1, &out4[obase + 1]);
}

// Fallback (ws too small / N not divisible by 8): direct fp32 gather.
__global__ __launch_bounds__(256) void ImportancePooling_28424093564958_f32(
    const float* __restrict__ x, const int* __restrict__ neighbors,
    const float* __restrict__ weights, float* __restrict__ out, int N) {
  const int wave_id = (int)((blockIdx.x * blockDim.x + threadIdx.x) >> 6);
  const int lane = threadIdx.x & 63;
  if (wave_id >= N) return;
  const long hbase = (long)wave_id * K_NBR;
  int packed;
  if (lane < K_NBR) {
    packed = __float_as_int(weights[hbase + lane]);
  } else {
    packed = neighbors[hbase + (lane - K_NBR)];
  }
  float acc = 0.0f, wsum = 0.0f;
#pragma unroll
  for (int k = 0; k < K_NBR; ++k) {
    const float wk = __int_as_float(__builtin_amdgcn_readlane(packed, k));
    const int idx = __builtin_amdgcn_readlane(packed, K_NBR + k);
    wsum += wk;
    acc += wk * x[(long)idx * D_FEAT + lane];
  }
  const float inv = (wsum > 0.0f) ? (1.0f / wsum) : 1.0f;
  out[(long)wave_id * D_FEAT + lane] = acc * inv;
}

extern "C" void kernel_launch(void* const* d_in, const int* in_sizes, int n_in,
                              void* d_out, int out_size, void* d_ws, size_t ws_size,
                              hipStream_t stream) {
  const float* x = (const float*)d_in[0];
  const int* neighbors = (const int*)d_in[1];
  const float* weights = (const float*)d_in[2];

  const int N = in_sizes[0] / D_FEAT;  // 100000
  const size_t xh_bytes = (size_t)N * D_FEAT * sizeof(__half);

  if (ws_size >= xh_bytes && (N % 8) == 0) {
    const int n4 = N * D_FEAT / 4;
    ImportancePooling_28424093564958_convert<<<(n4 + 255) / 256, 256, 0, stream>>>(
        (const f32x4*)x, (u32x2*)d_ws, n4);

    const int Nw = N / 8;
    const int block = 256;  // 4 waves/block
    const int grid = (Nw * 64 + block - 1) / block;
    ImportancePooling_28424093564958_kernel<<<grid, block, 0, stream>>>(
        (const u32x4*)d_ws, neighbors, weights, (f32x4*)d_out, Nw);
  } else {
    const int block = 256;
    const int grid = (N * 64 + block - 1) / block;
    ImportancePooling_28424093564958_f32<<<grid, block, 0, stream>>>(
        x, neighbors, weights, (float*)d_out, N);
  }
}